// Round 5
// baseline (184.979 us; speedup 1.0000x reference)
//
#include <hip/hip_runtime.h>

#define BN 4
#define CIN 512
#define H1 60
#define W1 80
#define P1 4800
#define H2 30
#define W2 40
#define P2 1200
#define HID 64
#define NCLS 11
#define HF 480
#define WF 640
#define PF 307200
#define THRESH 500

// ws layout (float element offsets)
#define WT1_OFF 0                   // 512*64 transposed w1 [c][o]
#define WT2_OFF 32768               // 512*64 transposed w2
#define F2_OFF  65536               // 4*1200*64 post-relu f2, pixel-major [b][p][o]
#define PART_OFF F2_OFF             // k4 bbox partials alias F2 (dead by then): 4800*45 ints
#define L_OFF   (65536 + 307200)    // 372736: 4*4800*12 coarse logits [b][p][k]

__device__ __forceinline__ void dma16(const float* g, float* l) {
    __builtin_amdgcn_global_load_lds(
        (const __attribute__((address_space(1))) void*)g,
        (__attribute__((address_space(3))) void*)l, 16, 0, 0);
}

// ---------------- K0: transpose weights ----------------
__global__ void k0_init(const float* __restrict__ w1, const float* __restrict__ w2,
                        float* __restrict__ ws) {
    int idx = blockIdx.x * 256 + threadIdx.x;
    if (idx < 32768) {
        int c = idx >> 6, o = idx & 63;
        ws[WT1_OFF + idx] = w1[o * CIN + c];
    } else {
        int j = idx - 32768;
        int c = j >> 6, o = j & 63;
        ws[WT2_OFF + j] = w2[o * CIN + c];
    }
}

// ---------------- K1: conv2 (512->64) + relu, pixel-major out ----------------
// 8-px tiles. 256 thr = 2 quads(8px) x 8 og x 16 ch(32c). grid 4*150=600.
__global__ __launch_bounds__(256, 4) void k1_conv2(const float* __restrict__ x,
                                                   const float* __restrict__ b2,
                                                   float* __restrict__ ws) {
    __shared__ float lds[8320];   // union: stage[2][2048] | partials[16][8][65]
    const float* wt = ws + WT2_OFF;
    float* f2o = ws + F2_OFF;
    int blk = blockIdx.x;
    int b = blk / 150, tile = blk % 150;
    int t = threadIdx.x;
    int l = t & 63, w = t >> 6;
    int q = t & 1, og = (t >> 1) & 7, ch = t >> 4;   // ch: 16 chunks of 32c
    int o0 = og * 8;
    int p0 = tile * 8;
    const float* xb = x + (size_t)b * CIN * P2 + p0;

    auto stage = [&](int s) {
        int buf = s & 1;
#pragma unroll
        for (int j = 0; j < 2; ++j) {
            int r0 = j * 128 + w * 32;         // wave-uniform; 32 rows per instr
            int r  = r0 + (l >> 1);
            int cg = (r >> 4) * 32 + s * 16 + (r & 15);   // chunk*32 + step c
            dma16(xb + (size_t)cg * P2 + (l & 1) * 4,
                  lds + buf * 2048 + r0 * 8);
        }
    };

    float acc[4][8];
#pragma unroll
    for (int j = 0; j < 4; ++j)
#pragma unroll
        for (int i = 0; i < 8; ++i) acc[j][i] = 0.f;

    stage(0);
    __syncthreads();
    const float* wp = wt + (ch * 32) * HID + o0;
    for (int s = 0; s < 2; ++s) {
        if (s < 1) stage(s + 1);
        const float* xs = lds + (s & 1) * 2048 + ch * 128 + q * 4;
#pragma unroll 4
        for (int cc = 0; cc < 16; ++cc) {
            float4 xv = *(const float4*)(xs + cc * 8);
            const float* wr = wp + (s * 16 + cc) * HID;
            float4 wa = *(const float4*)(wr);
            float4 wb = *(const float4*)(wr + 4);
            float w8[8] = {wa.x, wa.y, wa.z, wa.w, wb.x, wb.y, wb.z, wb.w};
            float x4[4] = {xv.x, xv.y, xv.z, xv.w};
#pragma unroll
            for (int j = 0; j < 4; ++j)
#pragma unroll
                for (int i = 0; i < 8; ++i) acc[j][i] = fmaf(w8[i], x4[j], acc[j][i]);
        }
        __syncthreads();
    }
#pragma unroll
    for (int j = 0; j < 4; ++j)
#pragma unroll
        for (int i = 0; i < 8; ++i)
            lds[ch * 520 + (q * 4 + j) * 65 + o0 + i] = acc[j][i];
    __syncthreads();

    if (t < 64) {
        int px = t >> 3, oo = (t & 7) * 8;     // 8 px x 8 og
        float v[8];
#pragma unroll
        for (int i = 0; i < 8; ++i) {
            float s = 0.f;
#pragma unroll
            for (int c = 0; c < 16; ++c) s += lds[c * 520 + px * 65 + oo + i];
            v[i] = fmaxf(s + b2[oo + i], 0.f);
        }
        float* outp = f2o + ((size_t)b * P2 + p0 + px) * HID + oo;
        *(float4*)outp = make_float4(v[0], v[1], v[2], v[3]);
        *(float4*)(outp + 4) = make_float4(v[4], v[5], v[6], v[7]);
    }
}

// ------- K2: conv1 + relu + 2x-bilerp(f2) add + 11-ch coarse logits -------
// 32-px tiles, grid 4*150=600. 256 thr = 8 q(4px) x 8 og x 4 ch(128c).
// x read DIRECT from global into ping-pong register groups (8 cc per group,
// 2 groups in flight) — no LDS staging, no main-loop barriers. Weights are
// L1/L2-hot broadcast loads. Epilogue identical to the verified R1 kernel.
__global__ __launch_bounds__(256, 4) void k2_conv1(const float* __restrict__ x,
                                                   const float* __restrict__ b1,
                                                   const float* __restrict__ wc,
                                                   const float* __restrict__ bc,
                                                   float* __restrict__ ws) {
    __shared__ float lds[8320];   // partials[4][32][65]
    const float* wt = ws + WT1_OFF;
    const float* f2 = ws + F2_OFF;
    float* lout = ws + L_OFF;
    int blk = blockIdx.x;
    int b = blk / 150, tile = blk % 150;
    int t = threadIdx.x;
    int q = t & 7, og = (t >> 3) & 7, ch = t >> 6;   // ch == wave, 128c chunk
    int o0 = og * 8;
    int p0 = tile * 32;
    const float* xc = x + (size_t)b * CIN * P1 + (size_t)(ch * 128) * P1 + p0 + q * 4;
    const float* wp = wt + (size_t)(ch * 128) * HID + o0;

    float acc[4][8];
#pragma unroll
    for (int j = 0; j < 4; ++j)
#pragma unroll
        for (int i = 0; i < 8; ++i) acc[j][i] = 0.f;

    // 128 channels = 16 groups of 8. Ping-pong register buffers xA/xB.
    auto loadg = [&](float4* xb, int g) {
        const float* p = xc + (size_t)g * (8 * P1);
#pragma unroll
        for (int i = 0; i < 8; ++i) xb[i] = *(const float4*)(p + (size_t)i * P1);
    };
    auto computeg = [&](const float4* xb, int g) {
        const float* wr0 = wp + g * 8 * HID;
#pragma unroll
        for (int i = 0; i < 8; ++i) {
            float4 wa = *(const float4*)(wr0 + i * HID);
            float4 wb = *(const float4*)(wr0 + i * HID + 4);
            float w8[8] = {wa.x, wa.y, wa.z, wa.w, wb.x, wb.y, wb.z, wb.w};
            float x4[4] = {xb[i].x, xb[i].y, xb[i].z, xb[i].w};
#pragma unroll
            for (int j = 0; j < 4; ++j)
#pragma unroll
                for (int i2 = 0; i2 < 8; ++i2) acc[j][i2] = fmaf(w8[i2], x4[j], acc[j][i2]);
        }
    };

    float4 xA[8], xB[8];
    loadg(xA, 0);
#pragma unroll 1
    for (int g = 0; g < 16; g += 2) {
        loadg(xB, min(g + 1, 15));
        computeg(xA, g);
        loadg(xA, min(g + 2, 15));
        computeg(xB, g + 1);
    }

#pragma unroll
    for (int j = 0; j < 4; ++j)
#pragma unroll
        for (int i = 0; i < 8; ++i)
            lds[ch * 2080 + (q * 4 + j) * 65 + o0 + i] = acc[j][i];
    __syncthreads();

    // combine 4 chunks + bias + relu + 2x-bilerp(f2) add; g -> lds[px*65+o]
    {
        int px = t >> 3;             // 0..31
        int oo = (t & 7) * 8;
        int p = p0 + px;
        int y = p / W1, xq = p - y * W1;
        float sy = fmaf((float)y, 0.5f, -0.25f);
        float fy = floorf(sy);
        float ty = sy - fy;
        int y0 = max(0, min(H2 - 1, (int)fy));
        int y1 = max(0, min(H2 - 1, (int)fy + 1));
        float sx = fmaf((float)xq, 0.5f, -0.25f);
        float fx = floorf(sx);
        float tx = sx - fx;
        int x0 = max(0, min(W2 - 1, (int)fx));
        int x1 = max(0, min(W2 - 1, (int)fx + 1));
        float wy0 = 1.f - ty, wx0 = 1.f - tx;
        const float* f2b = f2 + (size_t)b * P2 * HID;
        const float* r00 = f2b + (y0 * W2 + x0) * HID + oo;
        const float* r01 = f2b + (y0 * W2 + x1) * HID + oo;
        const float* r10 = f2b + (y1 * W2 + x0) * HID + oo;
        const float* r11 = f2b + (y1 * W2 + x1) * HID + oo;
#pragma unroll
        for (int i = 0; i < 8; ++i) {
            int a = px * 65 + oo + i;
            float s = lds[a] + lds[2080 + a] + lds[2 * 2080 + a] + lds[3 * 2080 + a];
            float f1v = fmaxf(s + b1[oo + i], 0.f);
            float v0 = r00[i] * wx0 + r01[i] * tx;
            float v1 = r10[i] * wx0 + r11[i] * tx;
            lds[a] = f1v + (v0 * wy0 + v1 * ty);
        }
    }
    __syncthreads();

    // coarse logits: l[px][k] = sum_o wc[k][o]*g[px][o] + bc[k]
    {
        int px2 = t & 31;
        int kg = t >> 5;                 // 0..7; second class kg+8 valid for kg<3
        int k2i = (kg < 3) ? kg + 8 : 8;
        float l1 = bc[kg];
        float l2 = bc[k2i];
#pragma unroll 8
        for (int o = 0; o < HID; ++o) {
            float gv = lds[px2 * 65 + o];
            l1 = fmaf(wc[kg * HID + o], gv, l1);
            l2 = fmaf(wc[k2i * HID + o], gv, l2);
        }
        float* lrow = lout + ((size_t)b * P1 + p0 + px2) * 12;
        lrow[kg] = l1;
        if (kg < 3) lrow[kg + 8] = l2;
        else if (kg == 3) lrow[11] = 0.f;   // pad slot so K4 can float4-load
    }
}

// ------- K4: 8x bilerp of logits + softmax + argmax + bbox partials -------
__global__ __launch_bounds__(256) void k4_main(float* __restrict__ out,
                                               float* __restrict__ ws) {
    __shared__ int s_cnt[9], s_x0[9], s_y0[9], s_x1[9], s_y1[9];
    const float* l = ws + L_OFF;
    int* partb = (int*)(ws + PART_OFF);
    int t = threadIdx.x;
    if (t < 9) { s_cnt[t] = 0; s_x0[t] = WF; s_y0[t] = HF; s_x1[t] = -1; s_y1[t] = -1; }
    __syncthreads();

    int fl = blockIdx.x * 256 + t;         // grid exactly covers 4*307200
    int b = fl / PF;
    int r = fl - b * PF;
    int Y = r / WF;
    int X = r - Y * WF;

    float sy = fmaf((float)Y, 0.125f, -0.4375f);
    float fy = floorf(sy);
    float ty = sy - fy;
    int y0 = max(0, min(H1 - 1, (int)fy));
    int y1 = max(0, min(H1 - 1, (int)fy + 1));
    float sx = fmaf((float)X, 0.125f, -0.4375f);
    float fx = floorf(sx);
    float tx = sx - fx;
    int x0 = max(0, min(W1 - 1, (int)fx));
    int x1 = max(0, min(W1 - 1, (int)fx + 1));
    float wy0 = 1.f - ty, wx0 = 1.f - tx;

    const float* lb = l + (size_t)b * P1 * 12;
    const float4* q00 = (const float4*)(lb + (y0 * W1 + x0) * 12);
    const float4* q01 = (const float4*)(lb + (y0 * W1 + x1) * 12);
    const float4* q10 = (const float4*)(lb + (y1 * W1 + x0) * 12);
    const float4* q11 = (const float4*)(lb + (y1 * W1 + x1) * 12);
    float l00[12], l01[12], l10[12], l11[12];
#pragma unroll
    for (int j = 0; j < 3; ++j) {
        ((float4*)l00)[j] = q00[j];
        ((float4*)l01)[j] = q01[j];
        ((float4*)l10)[j] = q10[j];
        ((float4*)l11)[j] = q11[j];
    }
    float li[11];
#pragma unroll
    for (int k = 0; k < 11; ++k) {
        float v0 = l00[k] * wx0 + l01[k] * tx;
        float v1 = l10[k] * wx0 + l11[k] * tx;
        li[k] = v0 * wy0 + v1 * ty;
    }
    int am = 0;
    float bm = li[0];
#pragma unroll
    for (int k = 1; k < 11; ++k) {
        if (li[k] > bm) { bm = li[k]; am = k; }   // strict > keeps first max
    }
    float e[11];
    float s = 0.f;
#pragma unroll
    for (int k = 0; k < 11; ++k) { e[k] = __expf(li[k] - bm); s += e[k]; }
    float rs = 1.f / s;
    size_t ob = (size_t)b * NCLS * PF + r;
#pragma unroll
    for (int k = 0; k < 11; ++k) out[ob + (size_t)k * PF] = e[k] * rs;
    out[(size_t)BN * NCLS * PF + fl] = (float)am;

    // per-wave bbox: each wave spans 64 consecutive X in a single row (640%64==0)
    int lane = t & 63;
    int X0 = X & ~63;
    for (int c = 1; c <= 9; ++c) {
        unsigned long long m = __ballot(am == c);
        if (m != 0ULL && lane == 0) {
            int ci = c - 1;
            atomicAdd(&s_cnt[ci], (int)__popcll(m));
            atomicMin(&s_x0[ci], X0 + __builtin_ctzll(m));
            atomicMax(&s_x1[ci], X0 + 63 - __builtin_clzll(m));
            atomicMin(&s_y0[ci], Y);
            atomicMax(&s_y1[ci], Y);
        }
    }
    __syncthreads();
    if (t < 9) {
        int* pr = partb + blockIdx.x * 45 + t * 5;
        pr[0] = s_cnt[t];
        pr[1] = s_x0[t];
        pr[2] = s_y0[t];
        pr[3] = s_x1[t];
        pr[4] = s_y1[t];
    }
}

// ---------------- K5: reduce bbox partials, emit rows ----------------
__global__ void k5_bbx(float* __restrict__ out, const float* __restrict__ ws) {
    const int* partb = (const int*)(ws + PART_OFF);
    int b = blockIdx.x / 9, c = blockIdx.x % 9;
    int t = threadIdx.x;  // 64
    int cnt = 0, mnx = WF, mny = HF, mxx = -1, mxy = -1;
    for (int i = t; i < 1200; i += 64) {
        const int* pr = partb + (size_t)(b * 1200 + i) * 45 + c * 5;
        cnt += pr[0];
        mnx = min(mnx, pr[1]);
        mny = min(mny, pr[2]);
        mxx = max(mxx, pr[3]);
        mxy = max(mxy, pr[4]);
    }
    for (int sft = 32; sft; sft >>= 1) {
        cnt += __shfl_xor(cnt, sft);
        mnx = min(mnx, __shfl_xor(mnx, sft));
        mny = min(mny, __shfl_xor(mny, sft));
        mxx = max(mxx, __shfl_xor(mxx, sft));
        mxy = max(mxy, __shfl_xor(mxy, sft));
    }
    if (t == 0) {
        float* row = out + (size_t)BN * NCLS * PF + (size_t)BN * PF + (size_t)(b * 9 + c) * 6;
        bool ok = cnt >= THRESH;
        row[0] = ok ? (float)b : -1.f;
        row[1] = ok ? (float)mnx : -1.f;
        row[2] = ok ? (float)mny : -1.f;
        row[3] = ok ? (float)mxx : -1.f;
        row[4] = ok ? (float)mxy : -1.f;
        row[5] = ok ? (float)(c + 1) : -1.f;
    }
}

extern "C" void kernel_launch(void* const* d_in, const int* in_sizes, int n_in,
                              void* d_out, int out_size, void* d_ws, size_t ws_size,
                              hipStream_t stream) {
    const float* f1 = (const float*)d_in[0];
    const float* f2 = (const float*)d_in[1];
    const float* w1 = (const float*)d_in[2];
    const float* b1 = (const float*)d_in[3];
    const float* w2 = (const float*)d_in[4];
    const float* b2 = (const float*)d_in[5];
    const float* wc = (const float*)d_in[6];
    const float* bc = (const float*)d_in[7];
    float* out = (float*)d_out;
    float* ws = (float*)d_ws;

    k0_init<<<dim3(256), dim3(256), 0, stream>>>(w1, w2, ws);
    k1_conv2<<<dim3(600), dim3(256), 0, stream>>>(f2, b2, ws);
    k2_conv1<<<dim3(600), dim3(256), 0, stream>>>(f1, b1, wc, bc, ws);
    k4_main<<<dim3(4800), dim3(256), 0, stream>>>(out, ws);
    k5_bbx<<<dim3(36), dim3(64), 0, stream>>>(out, ws);
}

// Round 6
// 166.452 us; speedup vs baseline: 1.1113x; 1.1113x over previous
//
#include <hip/hip_runtime.h>

#define BN 4
#define CIN 512
#define H1 60
#define W1 80
#define P1 4800
#define H2 30
#define W2 40
#define P2 1200
#define HID 64
#define NCLS 11
#define HF 480
#define WF 640
#define PF 307200
#define THRESH 500

// ws layout (float element offsets)
#define WT1_OFF 0                   // 512*64 transposed w1 [c][o]
#define WT2_OFF 32768               // 512*64 transposed w2
#define F2_OFF  65536               // 4*1200*64 post-relu f2, pixel-major [b][p][o]
#define PART_OFF F2_OFF             // k4 bbox partials alias F2 (dead by then): 4800*45 ints
#define L_OFF   (65536 + 307200)    // 372736: 4*4800*12 coarse logits [b][p][k]
#define PP_OFF  603136              // 4*2*4800*64 conv1 channel-half partials [b][hb][p][o]

__device__ __forceinline__ void dma16(const float* g, float* l) {
    __builtin_amdgcn_global_load_lds(
        (const __attribute__((address_space(1))) void*)g,
        (__attribute__((address_space(3))) void*)l, 16, 0, 0);
}

// ---------------- K0: transpose weights ----------------
__global__ void k0_init(const float* __restrict__ w1, const float* __restrict__ w2,
                        float* __restrict__ ws) {
    int idx = blockIdx.x * 256 + threadIdx.x;
    if (idx < 32768) {
        int c = idx >> 6, o = idx & 63;
        ws[WT1_OFF + idx] = w1[o * CIN + c];
    } else {
        int j = idx - 32768;
        int c = j >> 6, o = j & 63;
        ws[WT2_OFF + j] = w2[o * CIN + c];
    }
}

// ---------------- K1: conv2 (512->64) + relu, pixel-major out ----------------
// 8-px tiles. 256 thr = 2 quads(8px) x 8 og x 16 ch(32c). grid 4*150=600.
__global__ __launch_bounds__(256, 4) void k1_conv2(const float* __restrict__ x,
                                                   const float* __restrict__ b2,
                                                   float* __restrict__ ws) {
    __shared__ float lds[8320];   // union: stage[2][2048] | partials[16][8][65]
    const float* wt = ws + WT2_OFF;
    float* f2o = ws + F2_OFF;
    int blk = blockIdx.x;
    int b = blk / 150, tile = blk % 150;
    int t = threadIdx.x;
    int l = t & 63, w = t >> 6;
    int q = t & 1, og = (t >> 1) & 7, ch = t >> 4;   // ch: 16 chunks of 32c
    int o0 = og * 8;
    int p0 = tile * 8;
    const float* xb = x + (size_t)b * CIN * P2 + p0;

    auto stage = [&](int s) {
        int buf = s & 1;
#pragma unroll
        for (int j = 0; j < 2; ++j) {
            int r0 = j * 128 + w * 32;         // wave-uniform; 32 rows per instr
            int r  = r0 + (l >> 1);
            int cg = (r >> 4) * 32 + s * 16 + (r & 15);   // chunk*32 + step c
            dma16(xb + (size_t)cg * P2 + (l & 1) * 4,
                  lds + buf * 2048 + r0 * 8);
        }
    };

    float acc[4][8];
#pragma unroll
    for (int j = 0; j < 4; ++j)
#pragma unroll
        for (int i = 0; i < 8; ++i) acc[j][i] = 0.f;

    stage(0);
    __syncthreads();
    const float* wp = wt + (ch * 32) * HID + o0;
    for (int s = 0; s < 2; ++s) {
        if (s < 1) stage(s + 1);
        const float* xs = lds + (s & 1) * 2048 + ch * 128 + q * 4;
#pragma unroll 4
        for (int cc = 0; cc < 16; ++cc) {
            float4 xv = *(const float4*)(xs + cc * 8);
            const float* wr = wp + (s * 16 + cc) * HID;
            float4 wa = *(const float4*)(wr);
            float4 wb = *(const float4*)(wr + 4);
            float w8[8] = {wa.x, wa.y, wa.z, wa.w, wb.x, wb.y, wb.z, wb.w};
            float x4[4] = {xv.x, xv.y, xv.z, xv.w};
#pragma unroll
            for (int j = 0; j < 4; ++j)
#pragma unroll
                for (int i = 0; i < 8; ++i) acc[j][i] = fmaf(w8[i], x4[j], acc[j][i]);
        }
        __syncthreads();
    }
#pragma unroll
    for (int j = 0; j < 4; ++j)
#pragma unroll
        for (int i = 0; i < 8; ++i)
            lds[ch * 520 + (q * 4 + j) * 65 + o0 + i] = acc[j][i];
    __syncthreads();

    if (t < 64) {
        int px = t >> 3, oo = (t & 7) * 8;     // 8 px x 8 og
        float v[8];
#pragma unroll
        for (int i = 0; i < 8; ++i) {
            float s = 0.f;
#pragma unroll
            for (int c = 0; c < 16; ++c) s += lds[c * 520 + px * 65 + oo + i];
            v[i] = fmaxf(s + b2[oo + i], 0.f);
        }
        float* outp = f2o + ((size_t)b * P2 + p0 + px) * HID + oo;
        *(float4*)outp = make_float4(v[0], v[1], v[2], v[3]);
        *(float4*)(outp + 4) = make_float4(v[4], v[5], v[6], v[7]);
    }
}

// ------- K2a: conv1 channel-half partials; weights in LDS, x direct -------
// grid 1200 = 4 b x 2 hb x 150 tiles(32px). 256 thr = 8 q(4px) x 8 og x 4 ch(64c).
// Each wave stages its 64c x 64o weight slice (16 KB) into LDS via
// global_load_lds (linear, wave-uniform dest), then streams x from global
// with ping-pong register groups. Weight reads become ds_read_b128
// (broadcast across q, 2-way bank alias = free). Zero main-loop barriers.
__global__ __launch_bounds__(256, 2) void k2a_conv1(const float* __restrict__ x,
                                                    float* __restrict__ ws) {
    __shared__ float lds[16384];  // union: weights[4][64][64] | partials[4][32][65]
    const float* wtg = ws + WT1_OFF;
    float* pp = ws + PP_OFF;
    int blk = blockIdx.x;
    int b = blk / 300;
    int rem = blk - b * 300;
    int hb = rem / 150;
    int tile = rem - hb * 150;
    int t = threadIdx.x;
    int l = t & 63;
    int q = t & 7, og = (t >> 3) & 7, ch = t >> 6;   // ch == wave, 64c chunk
    int o0 = og * 8;
    int p0 = tile * 32;
    const float* xc = x + (size_t)b * CIN * P1 + (size_t)(hb * 256 + ch * 64) * P1
                    + p0 + q * 4;

    float4 xA[8], xB[8];
    auto loadg = [&](float4* xb, int g) {
        const float* p = xc + (size_t)g * (8 * P1);
#pragma unroll
        for (int i = 0; i < 8; ++i) xb[i] = *(const float4*)(p + (size_t)i * P1);
    };

    loadg(xA, 0);                      // first x group in flight early

    // stage this wave's weight slice: 64c x 64o = 4096 floats, linear
    {
        const float* src = wtg + hb * 16384 + ch * 4096;
#pragma unroll
        for (int i = 0; i < 16; ++i)
            dma16(src + i * 256 + l * 4, lds + ch * 4096 + i * 256);
    }
    __syncthreads();                   // weights staged (xA also drained)

    float acc[4][8];
#pragma unroll
    for (int j = 0; j < 4; ++j)
#pragma unroll
        for (int i = 0; i < 8; ++i) acc[j][i] = 0.f;

    const float* wl = lds + ch * 4096 + o0;
    auto computeg = [&](const float4* xb, int g) {
        const float* wr0 = wl + g * 8 * 64;
#pragma unroll
        for (int i = 0; i < 8; ++i) {
            float4 wa  = *(const float4*)(wr0 + i * 64);
            float4 wb4 = *(const float4*)(wr0 + i * 64 + 4);
            float w8[8] = {wa.x, wa.y, wa.z, wa.w, wb4.x, wb4.y, wb4.z, wb4.w};
            float x4[4] = {xb[i].x, xb[i].y, xb[i].z, xb[i].w};
#pragma unroll
            for (int j = 0; j < 4; ++j)
#pragma unroll
                for (int i2 = 0; i2 < 8; ++i2) acc[j][i2] = fmaf(w8[i2], x4[j], acc[j][i2]);
        }
    };

#pragma unroll 1
    for (int g = 0; g < 8; g += 2) {
        loadg(xB, min(g + 1, 7));
        computeg(xA, g);
        loadg(xA, min(g + 2, 7));
        computeg(xB, g + 1);
    }

    __syncthreads();                   // all weight reads done before aliasing
#pragma unroll
    for (int j = 0; j < 4; ++j)
#pragma unroll
        for (int i = 0; i < 8; ++i)
            lds[ch * 2080 + (q * 4 + j) * 65 + o0 + i] = acc[j][i];
    __syncthreads();

    // combine 4 chunks -> 256-channel partial; store raw (no bias/relu yet)
    {
        int px = t >> 3;             // 0..31
        int oo = (t & 7) * 8;
        float v[8];
#pragma unroll
        for (int i = 0; i < 8; ++i) {
            int a = px * 65 + oo + i;
            v[i] = lds[a] + lds[2080 + a] + lds[2 * 2080 + a] + lds[3 * 2080 + a];
        }
        float* outp = pp + ((size_t)(b * 2 + hb) * P1 + p0 + px) * HID + oo;
        *(float4*)outp = make_float4(v[0], v[1], v[2], v[3]);
        *(float4*)(outp + 4) = make_float4(v[4], v[5], v[6], v[7]);
    }
}

// ------- K2b: sum halves + bias + relu + 2x-bilerp(f2) add + coarse logits -------
// grid 600 = 4 b x 150 tiles(32px). 256 thr.
__global__ __launch_bounds__(256) void k2b_reduce(const float* __restrict__ b1,
                                                  const float* __restrict__ wc,
                                                  const float* __restrict__ bc,
                                                  float* __restrict__ ws) {
    __shared__ float g[2080];    // 32 px x 65
    const float* pp = ws + PP_OFF;
    const float* f2 = ws + F2_OFF;
    float* lout = ws + L_OFF;
    int blk = blockIdx.x;
    int b = blk / 150, tile = blk % 150;
    int t = threadIdx.x;
    int p0 = tile * 32;

    {
        int px = t >> 3;             // 0..31
        int oo = (t & 7) * 8;
        int p = p0 + px;
        const float* h0 = pp + ((size_t)(b * 2 + 0) * P1 + p) * HID + oo;
        const float* h1 = pp + ((size_t)(b * 2 + 1) * P1 + p) * HID + oo;
        float4 a0 = *(const float4*)h0;
        float4 a1 = *(const float4*)(h0 + 4);
        float4 c0 = *(const float4*)h1;
        float4 c1 = *(const float4*)(h1 + 4);
        float hs[8] = {a0.x + c0.x, a0.y + c0.y, a0.z + c0.z, a0.w + c0.w,
                       a1.x + c1.x, a1.y + c1.y, a1.z + c1.z, a1.w + c1.w};

        int y = p / W1, xq = p - y * W1;
        float sy = fmaf((float)y, 0.5f, -0.25f);
        float fy = floorf(sy);
        float ty = sy - fy;
        int y0 = max(0, min(H2 - 1, (int)fy));
        int y1 = max(0, min(H2 - 1, (int)fy + 1));
        float sx = fmaf((float)xq, 0.5f, -0.25f);
        float fx = floorf(sx);
        float tx = sx - fx;
        int x0 = max(0, min(W2 - 1, (int)fx));
        int x1 = max(0, min(W2 - 1, (int)fx + 1));
        float wy0 = 1.f - ty, wx0 = 1.f - tx;
        const float* f2b = f2 + (size_t)b * P2 * HID;
        const float* r00 = f2b + (y0 * W2 + x0) * HID + oo;
        const float* r01 = f2b + (y0 * W2 + x1) * HID + oo;
        const float* r10 = f2b + (y1 * W2 + x0) * HID + oo;
        const float* r11 = f2b + (y1 * W2 + x1) * HID + oo;
#pragma unroll
        for (int i = 0; i < 8; ++i) {
            float f1v = fmaxf(hs[i] + b1[oo + i], 0.f);
            float v0 = r00[i] * wx0 + r01[i] * tx;
            float v1 = r10[i] * wx0 + r11[i] * tx;
            g[px * 65 + oo + i] = f1v + (v0 * wy0 + v1 * ty);
        }
    }
    __syncthreads();

    // coarse logits: l[px][k] = sum_o wc[k][o]*g[px][o] + bc[k]
    {
        int px2 = t & 31;
        int kg = t >> 5;                 // 0..7; second class kg+8 valid for kg<3
        int k2i = (kg < 3) ? kg + 8 : 8;
        float l1 = bc[kg];
        float l2 = bc[k2i];
#pragma unroll 8
        for (int o = 0; o < HID; ++o) {
            float gv = g[px2 * 65 + o];
            l1 = fmaf(wc[kg * HID + o], gv, l1);
            l2 = fmaf(wc[k2i * HID + o], gv, l2);
        }
        float* lrow = lout + ((size_t)b * P1 + p0 + px2) * 12;
        lrow[kg] = l1;
        if (kg < 3) lrow[kg + 8] = l2;
        else if (kg == 3) lrow[11] = 0.f;   // pad slot so K4 can float4-load
    }
}

// ------- K4: 8x bilerp of logits + softmax + argmax + bbox partials -------
__global__ __launch_bounds__(256) void k4_main(float* __restrict__ out,
                                               float* __restrict__ ws) {
    __shared__ int s_cnt[9], s_x0[9], s_y0[9], s_x1[9], s_y1[9];
    const float* l = ws + L_OFF;
    int* partb = (int*)(ws + PART_OFF);
    int t = threadIdx.x;
    if (t < 9) { s_cnt[t] = 0; s_x0[t] = WF; s_y0[t] = HF; s_x1[t] = -1; s_y1[t] = -1; }
    __syncthreads();

    int fl = blockIdx.x * 256 + t;         // grid exactly covers 4*307200
    int b = fl / PF;
    int r = fl - b * PF;
    int Y = r / WF;
    int X = r - Y * WF;

    float sy = fmaf((float)Y, 0.125f, -0.4375f);
    float fy = floorf(sy);
    float ty = sy - fy;
    int y0 = max(0, min(H1 - 1, (int)fy));
    int y1 = max(0, min(H1 - 1, (int)fy + 1));
    float sx = fmaf((float)X, 0.125f, -0.4375f);
    float fx = floorf(sx);
    float tx = sx - fx;
    int x0 = max(0, min(W1 - 1, (int)fx));
    int x1 = max(0, min(W1 - 1, (int)fx + 1));
    float wy0 = 1.f - ty, wx0 = 1.f - tx;

    const float* lb = l + (size_t)b * P1 * 12;
    const float4* q00 = (const float4*)(lb + (y0 * W1 + x0) * 12);
    const float4* q01 = (const float4*)(lb + (y0 * W1 + x1) * 12);
    const float4* q10 = (const float4*)(lb + (y1 * W1 + x0) * 12);
    const float4* q11 = (const float4*)(lb + (y1 * W1 + x1) * 12);
    float l00[12], l01[12], l10[12], l11[12];
#pragma unroll
    for (int j = 0; j < 3; ++j) {
        ((float4*)l00)[j] = q00[j];
        ((float4*)l01)[j] = q01[j];
        ((float4*)l10)[j] = q10[j];
        ((float4*)l11)[j] = q11[j];
    }
    float li[11];
#pragma unroll
    for (int k = 0; k < 11; ++k) {
        float v0 = l00[k] * wx0 + l01[k] * tx;
        float v1 = l10[k] * wx0 + l11[k] * tx;
        li[k] = v0 * wy0 + v1 * ty;
    }
    int am = 0;
    float bm = li[0];
#pragma unroll
    for (int k = 1; k < 11; ++k) {
        if (li[k] > bm) { bm = li[k]; am = k; }   // strict > keeps first max
    }
    float e[11];
    float s = 0.f;
#pragma unroll
    for (int k = 0; k < 11; ++k) { e[k] = __expf(li[k] - bm); s += e[k]; }
    float rs = 1.f / s;
    size_t ob = (size_t)b * NCLS * PF + r;
#pragma unroll
    for (int k = 0; k < 11; ++k) out[ob + (size_t)k * PF] = e[k] * rs;
    out[(size_t)BN * NCLS * PF + fl] = (float)am;

    // per-wave bbox: each wave spans 64 consecutive X in a single row (640%64==0)
    int lane = t & 63;
    int X0 = X & ~63;
    for (int c = 1; c <= 9; ++c) {
        unsigned long long m = __ballot(am == c);
        if (m != 0ULL && lane == 0) {
            int ci = c - 1;
            atomicAdd(&s_cnt[ci], (int)__popcll(m));
            atomicMin(&s_x0[ci], X0 + __builtin_ctzll(m));
            atomicMax(&s_x1[ci], X0 + 63 - __builtin_clzll(m));
            atomicMin(&s_y0[ci], Y);
            atomicMax(&s_y1[ci], Y);
        }
    }
    __syncthreads();
    if (t < 9) {
        int* pr = partb + blockIdx.x * 45 + t * 5;
        pr[0] = s_cnt[t];
        pr[1] = s_x0[t];
        pr[2] = s_y0[t];
        pr[3] = s_x1[t];
        pr[4] = s_y1[t];
    }
}

// ---------------- K5: reduce bbox partials, emit rows ----------------
__global__ void k5_bbx(float* __restrict__ out, const float* __restrict__ ws) {
    const int* partb = (const int*)(ws + PART_OFF);
    int b = blockIdx.x / 9, c = blockIdx.x % 9;
    int t = threadIdx.x;  // 64
    int cnt = 0, mnx = WF, mny = HF, mxx = -1, mxy = -1;
    for (int i = t; i < 1200; i += 64) {
        const int* pr = partb + (size_t)(b * 1200 + i) * 45 + c * 5;
        cnt += pr[0];
        mnx = min(mnx, pr[1]);
        mny = min(mny, pr[2]);
        mxx = max(mxx, pr[3]);
        mxy = max(mxy, pr[4]);
    }
    for (int sft = 32; sft; sft >>= 1) {
        cnt += __shfl_xor(cnt, sft);
        mnx = min(mnx, __shfl_xor(mnx, sft));
        mny = min(mny, __shfl_xor(mny, sft));
        mxx = max(mxx, __shfl_xor(mxx, sft));
        mxy = max(mxy, __shfl_xor(mxy, sft));
    }
    if (t == 0) {
        float* row = out + (size_t)BN * NCLS * PF + (size_t)BN * PF + (size_t)(b * 9 + c) * 6;
        bool ok = cnt >= THRESH;
        row[0] = ok ? (float)b : -1.f;
        row[1] = ok ? (float)mnx : -1.f;
        row[2] = ok ? (float)mny : -1.f;
        row[3] = ok ? (float)mxx : -1.f;
        row[4] = ok ? (float)mxy : -1.f;
        row[5] = ok ? (float)(c + 1) : -1.f;
    }
}

extern "C" void kernel_launch(void* const* d_in, const int* in_sizes, int n_in,
                              void* d_out, int out_size, void* d_ws, size_t ws_size,
                              hipStream_t stream) {
    const float* f1 = (const float*)d_in[0];
    const float* f2 = (const float*)d_in[1];
    const float* w1 = (const float*)d_in[2];
    const float* b1 = (const float*)d_in[3];
    const float* w2 = (const float*)d_in[4];
    const float* b2 = (const float*)d_in[5];
    const float* wc = (const float*)d_in[6];
    const float* bc = (const float*)d_in[7];
    float* out = (float*)d_out;
    float* ws = (float*)d_ws;

    k0_init<<<dim3(256), dim3(256), 0, stream>>>(w1, w2, ws);
    k1_conv2<<<dim3(600), dim3(256), 0, stream>>>(f2, b2, ws);
    k2a_conv1<<<dim3(1200), dim3(256), 0, stream>>>(f1, ws);
    k2b_reduce<<<dim3(600), dim3(256), 0, stream>>>(b1, wc, bc, ws);
    k4_main<<<dim3(4800), dim3(256), 0, stream>>>(out, ws);
    k5_bbx<<<dim3(36), dim3(64), 0, stream>>>(out, ws);
}